// Round 1
// 404.580 us; speedup vs baseline: 1.0600x; 1.0600x over previous
//
#include <hip/hip_runtime.h>
#include <stdint.h>

// Problem constants (B=4, S=2048, K=4096, N=4096 -> M = B*S = 8192)
#define MDIM 8192
#define NDIM 4096
#define KDIM 4096

// GEMM tiling: 256x256 tile, BK=128 (i8 -> 128B rows), 512 threads = 8 waves
// (2M x 4N), per-wave 128x64 output via 4x2 grid of mfma_i32_32x32x32_i8.
// Double-buffered LDS (128 KiB), 8-phase schedule with counted vmcnt (T3+T4),
// st-style XOR swizzle (T2), setprio around MFMA clusters (T5), XCD-aware
// block swizzle (T1). Byte-isomorphic to the verified bf16 256^2 8-phase
// template (BK=64 bf16 == BK=128 i8: 128 B/row, 16 KiB half-tiles).
#define BM 256
#define BN 256
#define BK 128
#define NKT (KDIM / BK)   // 32 K-tiles; main loop does 2/iter

typedef __attribute__((ext_vector_type(4)))  int i32x4;
typedef __attribute__((ext_vector_type(16))) int i32x16;

#define AS1 __attribute__((address_space(1)))
#define AS3 __attribute__((address_space(3)))

__device__ __forceinline__ int clamp127(int v) {
    return v > 127 ? 127 : (v < -127 ? -127 : v);
}

// ---- x fp32 -> int8, per-row symmetric quant (row = 4096 elems) ----
// Unchanged from previous round (near BW floor; not this round's lever).
__global__ __launch_bounds__(256) void quant_x(
        const float* __restrict__ x, const float* __restrict__ sw,
        int8_t* __restrict__ Aq, float* __restrict__ scales) {
    const int row = blockIdx.x;
    const int t   = threadIdx.x;
    const float4* px = (const float4*)(x + (size_t)row * KDIM);

    float4 v[4];
#pragma unroll
    for (int j = 0; j < 4; j++) v[j] = px[t + 256 * j];

    float a = 0.f;
#pragma unroll
    for (int j = 0; j < 4; j++) {
        a = fmaxf(a, fabsf(v[j].x)); a = fmaxf(a, fabsf(v[j].y));
        a = fmaxf(a, fabsf(v[j].z)); a = fmaxf(a, fabsf(v[j].w));
    }
#pragma unroll
    for (int off = 32; off >= 1; off >>= 1)
        a = fmaxf(a, __shfl_xor(a, off));
    __shared__ float red[4];
    if ((t & 63) == 0) red[t >> 6] = a;
    __syncthreads();
    const float amax = fmaxf(fmaxf(red[0], red[1]), fmaxf(red[2], red[3]));
    const float inv  = (amax > 0.f) ? (127.0f / amax) : 0.f;
    if (t == 0) scales[row] = (amax * (1.0f / 127.0f)) * (*sw);

    int* out32 = (int*)(Aq + (size_t)row * KDIM);
#pragma unroll
    for (int j = 0; j < 4; j++) {
        int b0 = clamp127(__float2int_rn(v[j].x * inv));
        int b1 = clamp127(__float2int_rn(v[j].y * inv));
        int b2 = clamp127(__float2int_rn(v[j].z * inv));
        int b3 = clamp127(__float2int_rn(v[j].w * inv));
        out32[t + 256 * j] = (b0 & 255) | ((b1 & 255) << 8) | ((b2 & 255) << 16) | ((b3 & 255) << 24);
    }
}

// ---- qw int32 -> int8 (exact; values already in [-128,127]) ----
__global__ __launch_bounds__(256) void cvt_w(const int* __restrict__ qw, int8_t* __restrict__ Bq) {
    const long i = (long)blockIdx.x * 256 + threadIdx.x;
    int4 a = ((const int4*)qw)[i];
    ((int*)Bq)[i] = (a.x & 255) | ((a.y & 255) << 8) | ((a.z & 255) << 16) | ((a.w & 255) << 24);
}

// ======================= 256x256 8-phase i8 GEMM =======================
//
// LDS layout per tile: [256 rows][128 B], row split into 8 x 16B chunks,
// phys_chunk = logical_chunk ^ (row & 7)  (G4 swizzle for 128-B rows).
// Staging is linear global_load_lds (dest = base + tid*16); the swizzle is
// applied by pre-swizzling the per-thread GLOBAL source chunk (rule #21).
//
// Phase plan per iteration (tiles T0=2i in buf0, T1=2i+1 in buf1):
//   P1: rd A(mh0),B(n0) buf0 | stage (2i+1).Ah0          | mma(0,0)
//   P2: rd B(n1) buf0        | stage (2i+1).Ah1          | mma(0,1)
//   P3: rd A(mh1) buf0       | stage (2i+2).Bh0          | mma(1,1)
//   P4:                      | stage (2i+2).Bh1  vmcnt(4)| mma(1,0)
//   P5: rd A(mh0),B(n0) buf1 | stage (2i+2).Ah0          | mma(0,0)
//   P6: rd B(n1) buf1        | stage (2i+2).Ah1          | mma(0,1)
//   P7: rd A(mh1) buf1       | stage (2i+3).Bh0          | mma(1,1)
//   P8:                      | stage (2i+3).Bh1  vmcnt(4)| mma(1,0)
// Region safety: each stage targets a region whose last ds_read is >=1 phase
// earlier (reads drained by that phase's lgkmcnt(0) before its closing
// barrier). vmcnt(4)+barrier at P4/P8 guarantees the next tile's 8 staging
// loads (2 half-tiles in flight allowed) have landed before it is read.

#define BAR()   do { asm volatile("" ::: "memory"); __builtin_amdgcn_s_barrier(); asm volatile("" ::: "memory"); } while (0)
#define LGKM0() asm volatile("s_waitcnt lgkmcnt(0)" ::: "memory")
#define WAITV(n) asm volatile("s_waitcnt vmcnt(" #n ")" ::: "memory")

#define STAGE_A(buf, h, kt) do { \
    __builtin_amdgcn_global_load_lds((AS1 const void*)(gA + (size_t)((h) * 128) * KDIM + (kt) * 128), \
        (AS3 void*)(sA + (buf) * 32768 + (h) * 16384 + sdst), 16, 0, 0); \
    __builtin_amdgcn_global_load_lds((AS1 const void*)(gA + (size_t)((h) * 128 + 64) * KDIM + (kt) * 128), \
        (AS3 void*)(sA + (buf) * 32768 + (h) * 16384 + 8192 + sdst), 16, 0, 0); \
} while (0)

#define STAGE_B(buf, h, kt) do { \
    __builtin_amdgcn_global_load_lds((AS1 const void*)(gB + (size_t)((h) * 128) * KDIM + (kt) * 128), \
        (AS3 void*)(sB + (buf) * 32768 + (h) * 16384 + sdst), 16, 0, 0); \
    __builtin_amdgcn_global_load_lds((AS1 const void*)(gB + (size_t)((h) * 128 + 64) * KDIM + (kt) * 128), \
        (AS3 void*)(sB + (buf) * 32768 + (h) * 16384 + 8192 + sdst), 16, 0, 0); \
} while (0)

#define READ_A(buf, mh) do { \
    _Pragma("unroll") for (int q = 0; q < 2; ++q) \
    _Pragma("unroll") for (int ks = 0; ks < 4; ++ks) \
        aF[q][ks] = *(const i32x4*)(sA + (buf) * 32768 + rbA + ((mh) * 2 + q) * 4096 + co[ks]); \
} while (0)

#define READ_B(buf, ni) do { \
    _Pragma("unroll") for (int ks = 0; ks < 4; ++ks) \
        bF[ni][ks] = *(const i32x4*)(sB + (buf) * 32768 + rbB + (ni) * 4096 + co[ks]); \
} while (0)

#define MMA(mh, ni) do { \
    __builtin_amdgcn_s_setprio(1); \
    _Pragma("unroll") for (int ks = 0; ks < 4; ++ks) { \
        acc[(mh) * 2][ni]     = __builtin_amdgcn_mfma_i32_32x32x32_i8(aF[0][ks], bF[ni][ks], acc[(mh) * 2][ni], 0, 0, 0); \
        acc[(mh) * 2 + 1][ni] = __builtin_amdgcn_mfma_i32_32x32x32_i8(aF[1][ks], bF[ni][ks], acc[(mh) * 2 + 1][ni], 0, 0, 0); \
    } \
    __builtin_amdgcn_s_setprio(0); \
} while (0)

__global__ __launch_bounds__(512, 2) void gemm_bt_i8(
        const int8_t* __restrict__ A,    // [M,K] int8
        const int8_t* __restrict__ Bm,   // [N,K] int8
        const float* __restrict__ scales,// [M] = s_m * sw
        const float* __restrict__ bias,  // [N]
        float* __restrict__ C)           // [M,N] fp32
{
    __shared__ __align__(16) int8_t sA[2 * BM * BK];  // 64 KiB
    __shared__ __align__(16) int8_t sB[2 * BN * BK];  // 64 KiB

    const int tid  = threadIdx.x;
    const int wave = tid >> 6;
    const int lane = tid & 63;
    const int wr   = wave >> 2;       // 0..1  (M half)
    const int wc   = wave & 3;        // 0..3  (N quarter)
    const int l32  = lane & 31;
    const int hi   = lane >> 5;

    // T1: XCD-aware swizzle over 512 wgs (32 m-tiles x 16 n-tiles); 512%8==0.
    const int orig = blockIdx.y * 16 + blockIdx.x;
    const int nu   = (orig & 7) * 64 + (orig >> 3);
    const int m0   = (nu >> 4) * BM;
    const int n0   = (nu & 15) * BN;

    // ---- staging addresses (linear LDS dest, inverse-swizzled global src) ----
    const int trow = tid >> 3;                 // dest row within 64-row block
    const int slog = (tid & 7) ^ (trow & 7);   // source logical chunk
    const int8_t* gA = A  + (size_t)(m0 + trow) * KDIM + slog * 16;
    const int8_t* gB = Bm + (size_t)(n0 + trow) * KDIM + slog * 16;
    const int sdst = tid * 16;

    // ---- fragment read addresses ----
    const int swz = l32 & 7;
    const int rbA = (wr * 128 + l32) * BK;
    const int rbB = (wc * 64  + l32) * BK;
    int co[4];
#pragma unroll
    for (int ks = 0; ks < 4; ++ks) co[ks] = ((((ks << 1) | hi) ^ swz) << 4);

    i32x16 acc[4][2];
#pragma unroll
    for (int mi = 0; mi < 4; ++mi)
#pragma unroll
        for (int ni = 0; ni < 2; ++ni)
#pragma unroll
            for (int r = 0; r < 16; ++r) acc[mi][ni][r] = 0;

    i32x4 aF[2][4];   // current M-half: 2 mi x 4 k-slices
    i32x4 bF[2][4];   // both ni x 4 k-slices

    // ---- prologue: tile0 -> buf0, tile1.B -> buf1 (oldest-first order) ----
    STAGE_B(0, 0, 0); STAGE_B(0, 1, 0);
    STAGE_A(0, 0, 0); STAGE_A(0, 1, 0);
    STAGE_B(1, 0, 1); STAGE_B(1, 1, 1);
    WAITV(4);          // tile0's 8 loads landed; tile1.B (4) in flight
    BAR();

#pragma unroll 1
    for (int it = 0; it < NKT / 2 - 1; ++it) {     // 15 iterations, tiles 0..29
        const int t1 = 2 * it + 1, t2 = 2 * it + 2, t3 = 2 * it + 3;
        // P1
        READ_A(0, 0); READ_B(0, 0); STAGE_A(1, 0, t1); BAR(); LGKM0(); MMA(0, 0); BAR();
        // P2
        READ_B(0, 1);               STAGE_A(1, 1, t1); BAR(); LGKM0(); MMA(0, 1); BAR();
        // P3
        READ_A(0, 1);               STAGE_B(0, 0, t2); BAR(); LGKM0(); MMA(1, 1); BAR();
        // P4
        STAGE_B(0, 1, t2); WAITV(4); BAR();                           MMA(1, 0); BAR();
        // P5
        READ_A(1, 0); READ_B(1, 0); STAGE_A(0, 0, t2); BAR(); LGKM0(); MMA(0, 0); BAR();
        // P6
        READ_B(1, 1);               STAGE_A(0, 1, t2); BAR(); LGKM0(); MMA(0, 1); BAR();
        // P7
        READ_A(1, 1);               STAGE_B(1, 0, t3); BAR(); LGKM0(); MMA(1, 1); BAR();
        // P8
        STAGE_B(1, 1, t3); WAITV(4); BAR();                           MMA(1, 0); BAR();
    }

    // ---- tail: tiles 30 (buf0) and 31 (buf1); stage 31.A, then drain ----
    READ_A(0, 0); READ_B(0, 0); STAGE_A(1, 0, 31); BAR(); LGKM0(); MMA(0, 0); BAR();
    READ_B(0, 1);               STAGE_A(1, 1, 31); BAR(); LGKM0(); MMA(0, 1); BAR();
    READ_A(0, 1);                                  BAR(); LGKM0(); MMA(1, 1); BAR();
    WAITV(0); BAR();                                                MMA(1, 0); BAR();
    READ_A(1, 0); READ_B(1, 0);                    BAR(); LGKM0(); MMA(0, 0); BAR();
    READ_B(1, 1);                                  BAR(); LGKM0(); MMA(0, 1); BAR();
    READ_A(1, 1);                                         LGKM0(); MMA(1, 1);
    MMA(1, 0);

    // ---- epilogue ----
    // C/D 32x32 layout: col = l32, row = (r&3) + 8*(r>>2) + 4*hi  [m74/m101]
#pragma unroll
    for (int mi = 0; mi < 4; ++mi) {
        const int row_base = m0 + wr * 128 + mi * 32 + 4 * hi;
        float sc[16];
#pragma unroll
        for (int r = 0; r < 16; ++r)
            sc[r] = scales[row_base + (r & 3) + 8 * (r >> 2)];
#pragma unroll
        for (int ni = 0; ni < 2; ++ni) {
            const int col = n0 + wc * 64 + ni * 32 + l32;
            const float bc = bias[col];
#pragma unroll
            for (int r = 0; r < 16; ++r) {
                const int row = row_base + (r & 3) + 8 * (r >> 2);
                C[(size_t)row * NDIM + col] = (float)acc[mi][ni][r] * sc[r] + bc;
            }
        }
    }
}

// ---- correctness fallback if workspace is too small (not expected to run) ----
__global__ void gemm_naive_f32(const float* __restrict__ x, const int* __restrict__ qw,
                               const float* __restrict__ sw, const float* __restrict__ bias,
                               float* __restrict__ out) {
    size_t id = (size_t)blockIdx.x * blockDim.x + threadIdx.x;
    if (id >= (size_t)MDIM * NDIM) return;
    int m = (int)(id / NDIM);
    int n = (int)(id % NDIM);
    const float* xr = x + (size_t)m * KDIM;
    const int*   wr = qw + (size_t)n * KDIM;
    float acc = 0.f;
    for (int k = 0; k < KDIM; k++) acc += xr[k] * (float)wr[k];
    out[id] = acc * (*sw) + bias[n];
}

extern "C" void kernel_launch(void* const* d_in, const int* in_sizes, int n_in,
                              void* d_out, int out_size, void* d_ws, size_t ws_size,
                              hipStream_t stream) {
    const float* x    = (const float*)d_in[0];
    const int*   qw   = (const int*)d_in[1];
    const float* sw   = (const float*)d_in[2];
    const float* bias = (const float*)d_in[3];
    float* out = (float*)d_out;

    const size_t needA = (size_t)MDIM * KDIM;                  // 32 MiB int8
    const size_t needB = (size_t)NDIM * KDIM;                  // 16 MiB int8
    const size_t needS = (size_t)MDIM * sizeof(float);         // 32 KiB scales

    if (ws_size >= needA + needB + needS) {
        int8_t* Aq = (int8_t*)d_ws;
        int8_t* Bq = Aq + needA;
        float*  scales = (float*)(Bq + needB);

        quant_x<<<MDIM, 256, 0, stream>>>(x, sw, Aq, scales);
        const long nw4 = (long)NDIM * KDIM / 4;
        cvt_w<<<(int)(nw4 / 256), 256, 0, stream>>>(qw, Bq);

        dim3 grid(NDIM / BN, MDIM / BM);                       // (16, 32) = 512 blocks
        gemm_bt_i8<<<grid, 512, 0, stream>>>(Aq, Bq, scales, bias, out);
    } else {
        size_t total = (size_t)MDIM * NDIM;
        gemm_naive_f32<<<(total + 255) / 256, 256, 0, stream>>>(x, qw, sw, bias, out);
    }
}